// Round 18
// baseline (79.940 us; speedup 1.0000x reference)
//
#include <hip/hip_runtime.h>

#define N_ 256
#define L_ 4096
#define DM_ 2048
#define STEPF (1.0f / 4096.0f)
#define NW 10
#define NV 5
#define RQN 4608

typedef short bf16x8 __attribute__((ext_vector_type(8)));
typedef float f32x4 __attribute__((ext_vector_type(4)));
typedef unsigned int uint32;

__device__ __forceinline__ uint32 bf16rne(float f) {
    uint32 u = __builtin_bit_cast(uint32, f);
    return (u + 0x7FFFu + ((u >> 16) & 1u)) >> 16;
}
__device__ __forceinline__ float rdlane(float v, int l) {
    return __builtin_bit_cast(float, __builtin_amdgcn_readlane(__builtin_bit_cast(int, v), l));
}
__device__ __forceinline__ float hif(float x) {
    return __builtin_bit_cast(float, __builtin_bit_cast(uint32, x) & 0xFFFF0000u);
}
#define PK2(LO, HI) __builtin_amdgcn_perm(__builtin_bit_cast(uint32, (HI)), \
                                          __builtin_bit_cast(uint32, (LO)), 0x07060302u)

// ---------------- Phase 1: build K (block 0) + pack y->bf16 (blocks 1..256) ----------------
// (bit-identical to R17's kernel)
__global__ __launch_bounds__(1024) void k_build(const float* __restrict__ Araw,
                                                const float* __restrict__ Bv,
                                                const float* __restrict__ Cv,
                                                const float* __restrict__ yf,
                                                uint2* __restrict__ Rqg,
                                                uint4* __restrict__ ybf) {
    const int tid = threadIdx.x;
    if (blockIdx.x > 0) {
        const size_t base = (size_t)(blockIdx.x - 1) * 32768;
        const float4* yin = (const float4*)(yf + base);
        uint4* yo = ybf + base / 8;
#pragma unroll
        for (int i = 0; i < 4; ++i) {
            int c = i * 1024 + tid;
            float4 q0 = yin[2 * c], q1 = yin[2 * c + 1];
            uint4 o; o.x = PK2(q0.x, q0.y); o.y = PK2(q0.z, q0.w);
                     o.z = PK2(q1.x, q1.y); o.w = PK2(q1.z, q1.w);
            yo[c] = o;
        }
        return;
    }

    __shared__ float sm[39168];
    float* kry = sm;
    float* red = sm + 3840;
    float* Wl  = sm + 5888;
    float* Vt  = sm + 22528;
    float* Kf  = sm;

    const int j = tid & 255, seg = tid >> 8, lane = tid & 63;
    const int e = 64 * seg + lane;
    float a[64];

#define DOT64(S0, S1, VV) { \
    _Pragma("unroll") \
    for (int m = 0; m < 64; m += 2) { \
        S0 = fmaf(rdlane(VV, m), a[m], S0); \
        S1 = fmaf(rdlane(VV, m + 1), a[m + 1], S1); \
    } }

#pragma unroll
    for (int m = 0; m < 64; ++m) a[m] = Araw[(64 * seg + m) * 256 + j];
    if (tid < 256) kry[tid] = Cv[tid];
    __syncthreads();
    const float WSC = 4032.0f / 4096.0f;
    {
        float vv = kry[e];
        for (int n = 1; n < NW; ++n) {
            float s0 = 0.f, s1 = 0.f;
            DOT64(s0, s1, vv)
            float* rb = red + (n & 1) * 1024;
            rb[seg * 256 + j] = s0 + s1;
            __syncthreads();
            float sc = WSC / (float)n;
            vv = (rb[e] + rb[256 + e] + rb[512 + e] + rb[768 + e]) * sc;
            if (tid < 256)
                kry[n * 256 + tid] = (rb[tid] + rb[256 + tid] + rb[512 + tid] + rb[768 + tid]) * sc;
        }
    }
    __syncthreads();
    {
        float kj[NW];
#pragma unroll
        for (int n = 0; n < NW; ++n) kj[n] = kry[n * 256 + j];
#pragma unroll
        for (int u = 0; u < 16; ++u) {
            int q = seg + 4 * u;
            float c = (float)q * (1.0f / 63.0f);
            float h = kj[NW - 1];
#pragma unroll
            for (int n = NW - 2; n >= 0; --n) h = fmaf(c, h, kj[n]);
            Wl[q * 260 + j] = h;
        }
    }
    {
        const float4* Ar = (const float4*)(Araw + (size_t)j * 256 + 64 * seg);
#pragma unroll
        for (int m4 = 0; m4 < 16; ++m4) {
            float4 q4 = Ar[m4];
            a[4 * m4] = q4.x; a[4 * m4 + 1] = q4.y; a[4 * m4 + 2] = q4.z; a[4 * m4 + 3] = q4.w;
        }
    }
    const float ms = 0.5f * STEPF;
    const float bve = Bv[e];
    {
        float vv = bve;
        for (int it = 0; it < 2; ++it) {
            float s0 = 0.f, s1 = 0.f;
            DOT64(s0, s1, vv)
            float* rb = red + (it & 1) * 1024;
            rb[seg * 256 + j] = s0 + s1;
            __syncthreads();
            vv = fmaf(ms, rb[e] + rb[256 + e] + rb[512 + e] + rb[768 + e], bve);
            if (it == 1 && tid < 256) {
                float su = rb[tid] + rb[256 + tid] + rb[512 + tid] + rb[768 + tid];
                kry[tid] = STEPF * fmaf(ms, su, Bv[tid]);
            }
        }
    }
    __syncthreads();
    const float VSC = 63.0f / 4096.0f;
    {
        float vv = kry[e];
        for (int n = 1; n < NV; ++n) {
            float s0 = 0.f, s1 = 0.f;
            DOT64(s0, s1, vv)
            float* rb = red + (n & 1) * 1024;
            rb[seg * 256 + j] = s0 + s1;
            __syncthreads();
            float sc = VSC / (float)n;
            vv = (rb[e] + rb[256 + e] + rb[512 + e] + rb[768 + e]) * sc;
            if (tid < 256)
                kry[n * 256 + tid] = (rb[tid] + rb[256 + tid] + rb[512 + tid] + rb[768 + tid]) * sc;
        }
    }
    __syncthreads();
    {
        float kj[NV];
#pragma unroll
        for (int n = 0; n < NV; ++n) kj[n] = kry[n * 256 + j];
#pragma unroll
        for (int u = 0; u < 16; ++u) {
            int r = seg + 4 * u;
            float c = (float)r * (1.0f / 63.0f);
            float h = kj[NV - 1];
#pragma unroll
            for (int n = NV - 2; n >= 0; --n) h = fmaf(c, h, kj[n]);
            Vt[r * 260 + j] = h;
        }
    }
    __syncthreads();
    {
        const int wv = tid >> 6;
        const int qt = wv >> 2, rt = wv & 3;
        const int n16 = lane & 15, g4 = lane >> 4;
        const int q = 16 * qt + n16;
        const int r = 16 * rt + n16;
        f32x4 ac = (f32x4){0.f, 0.f, 0.f, 0.f};
        for (int s = 0; s < 8; ++s) {
            const int kk = 32 * s + 8 * g4;
            float4 w0 = *(const float4*)&Wl[q * 260 + kk];
            float4 w1 = *(const float4*)&Wl[q * 260 + kk + 4];
            float4 v0 = *(const float4*)&Vt[r * 260 + kk];
            float4 v1 = *(const float4*)&Vt[r * 260 + kk + 4];
            uint4 uh; uh.x = PK2(w0.x, w0.y); uh.y = PK2(w0.z, w0.w);
                      uh.z = PK2(w1.x, w1.y); uh.w = PK2(w1.z, w1.w);
            float l0 = w0.x - hif(w0.x), l1 = w0.y - hif(w0.y);
            float l2 = w0.z - hif(w0.z), l3 = w0.w - hif(w0.w);
            float l4 = w1.x - hif(w1.x), l5 = w1.y - hif(w1.y);
            float l6 = w1.z - hif(w1.z), l7 = w1.w - hif(w1.w);
            uint4 ul; ul.x = PK2(l0, l1); ul.y = PK2(l2, l3);
                      ul.z = PK2(l4, l5); ul.w = PK2(l6, l7);
            uint4 uv; uv.x = PK2(v0.x, v0.y); uv.y = PK2(v0.z, v0.w);
                      uv.z = PK2(v1.x, v1.y); uv.w = PK2(v1.z, v1.w);
            ac = __builtin_amdgcn_mfma_f32_16x16x32_bf16(__builtin_bit_cast(bf16x8, uh),
                                                         __builtin_bit_cast(bf16x8, uv), ac, 0, 0, 0);
            ac = __builtin_amdgcn_mfma_f32_16x16x32_bf16(__builtin_bit_cast(bf16x8, ul),
                                                         __builtin_bit_cast(bf16x8, uv), ac, 0, 0, 0);
        }
#pragma unroll
        for (int jj = 0; jj < 4; ++jj)
            Kf[(16 * qt + 4 * g4 + jj) * 64 + r] = ac[jj];
    }
    __syncthreads();
    for (int i = tid; i < RQN; i += 1024) {
        int aa = 4095 - i;
        uint32 e0 = (aa >= 0) ? bf16rne(Kf[aa]) : 0u;
        uint32 e1 = (aa >= 1) ? bf16rne(Kf[aa - 1]) : 0u;
        uint32 e2 = (aa >= 2) ? bf16rne(Kf[aa - 2]) : 0u;
        uint32 e3 = (aa >= 3) ? bf16rne(Kf[aa - 3]) : 0u;
        uint2 v; v.x = e0 | (e1 << 16); v.y = e2 | (e3 << 16);
        Rqg[i] = v;
    }
#undef DOT64
}

// ---------------- Phase 2: MFMA causal conv, T=12 (<=128 VGPR -> 3-4 waves/SIMD) ----------------
// Wave-scaling law (R9/R11/R16): per-wave-step time 970/363/150 cyc at 1/2/4 waves/SIMD ->
// stalls fill linearly with occupancy.  Occupancy quantum halves at VGPR {64,128,256}, so
// T=16 (~150 regs) is locked at 2/SIMD.  T=12 fits <=128 regs: 192-col strips v=0..19,
// pairs (20-by, by-1) -> 63 steps/wave const, j-split 2.  Tail [3840,4096): by=0 blocks,
// T=8 x 2 col-halves, full j (longest waves, dispatched first).  Grid (64,11)=704 blocks.
__global__ __launch_bounds__(256, 4) void k_conv(const uint2* __restrict__ Rqg,
                                                 const uint4* __restrict__ ybf,
                                                 const float* __restrict__ y,
                                                 const float* __restrict__ Dp,
                                                 float* __restrict__ out) {
    __shared__ uint2 Rq[RQN];
    __shared__ f32x4 mbuf[2][4][64];
    const int tid = threadIdx.x;
#pragma unroll
    for (int i = 0; i < RQN / 256; ++i) Rq[i * 256 + tid] = Rqg[i * 256 + tid];
    __syncthreads();

    const int w = tid >> 6, lane = tid & 63;
    const int n = lane & 15, g = lane >> 4;
    const int by = (int)blockIdx.y;                   // 0..10
    const int bx = (int)blockIdx.x;                   // 0..63
    const int ds = w & 1;
    const int d0w = bx * 32 + ds * 16;
    const int d = d0w + n;
    const uint4* __restrict__ ybr = ybf + (size_t)d * (L_ / 8);
    const float D0 = Dp[0];

#define LOADF(SL, I0) { \
    uint2 u0 = Rq[(I0)]; uint2 u1 = Rq[(I0) + 4]; \
    uint4 uu; uu.x = u0.x; uu.y = u0.y; uu.z = u1.x; uu.w = u1.y; \
    fr[SL] = __builtin_bit_cast(bf16x8, uu); }
#define MF(TI, SL) acc[TI] = __builtin_amdgcn_mfma_f32_16x16x32_bf16(av, fr[SL], acc[TI], 0, 0, 0);

    if (by == 0) {
        // ---- T=8 tail: cols [3840+128h, +128), full j ----
        const int h = w >> 1;
        const int t0 = 3840 + 128 * h;
        const int S = 124 + 4 * h;       // 124 (h=0) or 128 (h=1), both %4==0
        f32x4 acc[8];
#pragma unroll
        for (int i = 0; i < 8; ++i) acc[i] = (f32x4){0.f, 0.f, 0.f, 0.f};
        bf16x8 fr[8], av;
        uint4 ave, avo;
        const int B0 = 4095 - t0 - n + 8 * g;
#pragma unroll
        for (int ti = 0; ti < 8; ++ti) LOADF(ti, B0 - 16 * ti)
        ave = ybr[g]; avo = ybr[4 + g];
        int bcur = B0, yn = 8 + g;

#define STEP8E(S0,S1,S2,S3,S4,S5,S6,S7) { \
    av = __builtin_bit_cast(bf16x8, ave); \
    MF(6, S6) MF(7, S7) \
    LOADF(S6, bcur + 32) LOADF(S7, bcur + 16) \
    ave = ybr[yn & 511]; yn += 4; bcur += 32; \
    MF(0,S0) MF(1,S1) MF(2,S2) MF(3,S3) MF(4,S4) MF(5,S5) \
}
#define STEP8O(S0,S1,S2,S3,S4,S5,S6,S7) { \
    av = __builtin_bit_cast(bf16x8, avo); \
    MF(6, S6) MF(7, S7) \
    LOADF(S6, bcur + 32) LOADF(S7, bcur + 16) \
    avo = ybr[yn & 511]; yn += 4; bcur += 32; \
    MF(0,S0) MF(1,S1) MF(2,S2) MF(3,S3) MF(4,S4) MF(5,S5) \
}
        const int nr = S >> 2;
        for (int it = 0; it < nr; ++it) {
            STEP8E(0,1,2,3,4,5,6,7)
            STEP8O(6,7,0,1,2,3,4,5)
            STEP8E(4,5,6,7,0,1,2,3)
            STEP8O(2,3,4,5,6,7,0,1)
        }
#undef STEP8E
#undef STEP8O
#pragma unroll
        for (int ti = 0; ti < 8; ++ti) {
            int tcol = t0 + 16 * ti + n;
#pragma unroll
            for (int r = 0; r < 4; ++r) {
                int dr = d0w + 4 * g + r;
                size_t ix = (size_t)dr * L_ + tcol;
                out[ix] = acc[ti][r] + D0 * y[ix];
            }
        }
        return;
    }

    // ---- T=12 main: strips v1 = 20-by, v2 = by-1 (192 cols each), j-split 2 ----
    const int jq = w >> 1;
    for (int strip = 0; strip < 2; ++strip) {
        const int v = strip ? (by - 1) : (20 - by);
        const int t0 = 192 * v;
        const int Sh = 3 * (v + 1);       // per-wave j-steps (half of strip total)
        const int s0 = jq * Sh;

        f32x4 acc[12];
#pragma unroll
        for (int i = 0; i < 12; ++i) acc[i] = (f32x4){0.f, 0.f, 0.f, 0.f};
        bf16x8 fr[12], av;
        uint4 ave, avo;

        const int B0 = 4095 - t0 - n + 8 * g + 32 * s0;
#pragma unroll
        for (int ti = 0; ti < 12; ++ti) LOADF(ti, B0 - 16 * ti)
        ave = ybr[(4 * s0 + g) & 511]; avo = ybr[(4 * s0 + 4 + g) & 511];
        int bcur = B0, yn = 4 * s0 + 8 + g;

#define STEP12E(S0,S1,S2,S3,S4,S5,S6,S7,S8,S9,S10,S11) { \
    av = __builtin_bit_cast(bf16x8, ave); \
    MF(10, S10) MF(11, S11) \
    LOADF(S10, bcur + 32) LOADF(S11, bcur + 16) \
    ave = ybr[yn & 511]; yn += 4; bcur += 32; \
    MF(0,S0) MF(1,S1) MF(2,S2) MF(3,S3) MF(4,S4) MF(5,S5) \
    MF(6,S6) MF(7,S7) MF(8,S8) MF(9,S9) \
}
#define STEP12O(S0,S1,S2,S3,S4,S5,S6,S7,S8,S9,S10,S11) { \
    av = __builtin_bit_cast(bf16x8, avo); \
    MF(10, S10) MF(11, S11) \
    LOADF(S10, bcur + 32) LOADF(S11, bcur + 16) \
    avo = ybr[yn & 511]; yn += 4; bcur += 32; \
    MF(0,S0) MF(1,S1) MF(2,S2) MF(3,S3) MF(4,S4) MF(5,S5) \
    MF(6,S6) MF(7,S7) MF(8,S8) MF(9,S9) \
}
        // rotation period 6; Sh = 3(v+1): n6 full rounds + rem3 (first 3 phases) if v even
        const int n6 = Sh / 6;
        for (int it = 0; it < n6; ++it) {
            STEP12E(0,1,2,3,4,5,6,7,8,9,10,11)
            STEP12O(10,11,0,1,2,3,4,5,6,7,8,9)
            STEP12E(8,9,10,11,0,1,2,3,4,5,6,7)
            STEP12O(6,7,8,9,10,11,0,1,2,3,4,5)
            STEP12E(4,5,6,7,8,9,10,11,0,1,2,3)
            STEP12O(2,3,4,5,6,7,8,9,10,11,0,1)
        }
        if (Sh - 6 * n6) {   // rem == 3
            STEP12E(0,1,2,3,4,5,6,7,8,9,10,11)
            STEP12O(10,11,0,1,2,3,4,5,6,7,8,9)
            STEP12E(8,9,10,11,0,1,2,3,4,5,6,7)
        }
#undef STEP12E
#undef STEP12O

        // ---- merge j-halves (3 rounds of 4 accs), jq=0 stores ----
#pragma unroll
        for (int rr = 0; rr < 3; ++rr) {
            if (jq == 1) {
#pragma unroll
                for (int i = 0; i < 4; ++i) mbuf[ds][i][lane] = acc[4 * rr + i];
            }
            __syncthreads();
            if (jq == 0) {
#pragma unroll
                for (int i = 0; i < 4; ++i) {
                    f32x4 m = mbuf[ds][i][lane];
                    acc[4 * rr + i][0] += m[0]; acc[4 * rr + i][1] += m[1];
                    acc[4 * rr + i][2] += m[2]; acc[4 * rr + i][3] += m[3];
                }
            }
            __syncthreads();
        }
        if (jq == 0) {
#pragma unroll
            for (int ti = 0; ti < 12; ++ti) {
                int tcol = t0 + 16 * ti + n;
#pragma unroll
                for (int r = 0; r < 4; ++r) {
                    int dr = d0w + 4 * g + r;
                    size_t ix = (size_t)dr * L_ + tcol;
                    out[ix] = acc[ti][r] + D0 * y[ix];
                }
            }
        }
    }
#undef MF
#undef LOADF
}

// ---------------- host ----------------

extern "C" void kernel_launch(void* const* d_in, const int* in_sizes, int n_in,
                              void* d_out, int out_size, void* d_ws, size_t ws_size,
                              hipStream_t stream) {
    const float* y  = (const float*)d_in[0];
    const float* A  = (const float*)d_in[1];
    const float* Bv = (const float*)d_in[2];
    const float* Cv = (const float*)d_in[3];
    const float* Dp = (const float*)d_in[4];
    float* out = (float*)d_out;
    char* w = (char*)d_ws;
    uint2* Rqg = (uint2*)w;                       // 36,864 B
    uint4* ybf = (uint4*)(w + 36864);             // 16,777,216 B (2048x4096 bf16)

    k_build<<<dim3(257), dim3(1024), 0, stream>>>(A, Bv, Cv, y, Rqg, ybf);
    k_conv<<<dim3(64, 11), dim3(256), 0, stream>>>(Rqg, ybf, y, Dp, out);

    (void)in_sizes; (void)n_in; (void)out_size; (void)ws_size;
}